// Round 12
// baseline (403.696 us; speedup 1.0000x reference)
//
#include <hip/hip_runtime.h>
#include <cstdint>

#define NB 2
#define NSEQ 2048
#define CDIM 768
#define NH 12
#define HD 64
#define NTOK (NB*NSEQ)        // 4096
#define QKV_COLS (3*CDIM)     // 2304
#define NBLK ((NSEQ/128)*NH*NB) // 384 attn blocks (128 queries each)

typedef short bf16x8 __attribute__((ext_vector_type(8)));
typedef short bf16x4 __attribute__((ext_vector_type(4)));
typedef float f32x4  __attribute__((ext_vector_type(4)));
typedef short short4v __attribute__((ext_vector_type(4)));
typedef unsigned int uint4v __attribute__((ext_vector_type(4)));

#define MFMA16(a,b,c) __builtin_amdgcn_mfma_f32_16x16x32_bf16(a,b,c,0,0,0)

__device__ __forceinline__ short f2b(float f) {
    uint32_t u = __builtin_bit_cast(uint32_t, f);
    u += 0x7fffu + ((u >> 16) & 1u);
    return (short)(u >> 16);
}
__device__ __forceinline__ unsigned pack2(float a, float b) {
    unsigned ua = __builtin_bit_cast(unsigned, a) + 0x7fffu;
    unsigned ub = __builtin_bit_cast(unsigned, b) + 0x7fffu;
    return __builtin_amdgcn_perm(ub, ua, 0x07060302u);
}
__device__ __forceinline__ void gll16(const short* g, short* l) {
    __builtin_amdgcn_global_load_lds(
        (const __attribute__((address_space(1))) unsigned int*)g,
        (__attribute__((address_space(3))) unsigned int*)l, 16, 0, 0);
}

// ---------------------------------------------------------------------------
// Merged prep: x fp32->bf16 (blocks 0..3071), w_qkv T (..4799), w_proj T (..5375)
// ---------------------------------------------------------------------------
__global__ __launch_bounds__(256) void prep_kernel(
    const float* __restrict__ x, const float* __restrict__ w_qkv,
    const float* __restrict__ w_proj,
    short* __restrict__ xb, short* __restrict__ wqt, short* __restrict__ wpt)
{
    __shared__ float tile[32][33];
    const int bid = blockIdx.x, t = threadIdx.x;
    if (bid < 3072) {
        int i = bid * 256 + t;
        float4 v = ((const float4*)x)[i];
        short4v o = { f2b(v.x), f2b(v.y), f2b(v.z), f2b(v.w) };
        ((short4v*)xb)[i] = o;
        return;
    }
    const float* w; short* wt; int K, NC, n0, k0;
    if (bid < 3072 + 1728) {
        int r = bid - 3072;
        w = w_qkv; wt = wqt; K = CDIM; NC = QKV_COLS;
        n0 = (r % 72) * 32; k0 = (r / 72) * 32;
    } else {
        int r = bid - 4800;
        w = w_proj; wt = wpt; K = CDIM; NC = CDIM;
        n0 = (r % 24) * 32; k0 = (r / 24) * 32;
    }
    #pragma unroll
    for (int i = 0; i < 4; ++i) {
        int idx = t + i * 256; int r = idx >> 5, c = idx & 31;
        tile[r][c] = w[(size_t)(k0 + r) * NC + n0 + c];
    }
    __syncthreads();
    #pragma unroll
    for (int i = 0; i < 4; ++i) {
        int idx = t + i * 256; int r = idx >> 5, c = idx & 31;
        wt[(size_t)(n0 + r) * K + k0 + c] = f2b(tile[c][r]);
    }
}

// ---------------------------------------------------------------------------
// GEMM 64x128 tile (cols x tokens), dbuf BK=32, 1 barrier/stage (round 11).
// ---------------------------------------------------------------------------
#define GSTAGE(K0, BUF) do {                                                     \
    gll16(ag + (K0), As + (BUF)*4096 + wid*512);                                 \
    gll16(bg0 + (K0), Bs + (BUF)*8192 + wid*1024);                               \
    gll16(bg1 + (K0), Bs + (BUF)*8192 + wid*1024 + 512);                         \
} while (0)

#define GCOMP(BUF) do {                                                          \
    const short* A_ = As + (BUF)*4096;                                           \
    const short* B_ = Bs + (BUF)*8192;                                           \
    bf16x8 af_[2], bf_[4];                                                       \
    _Pragma("unroll")                                                            \
    for (int i = 0; i < 2; ++i)                                                  \
        af_[i] = *(const bf16x8*)&A_[(wA*32 + i*16 + l16) * 32 + quad*8];        \
    _Pragma("unroll")                                                            \
    for (int j = 0; j < 4; ++j)                                                  \
        bf_[j] = *(const bf16x8*)&B_[(wB*64 + j*16 + l16) * 32 + quad*8];        \
    _Pragma("unroll")                                                            \
    for (int i = 0; i < 2; ++i)                                                  \
        _Pragma("unroll")                                                        \
        for (int j = 0; j < 4; ++j)                                              \
            acc[i][j] = MFMA16(af_[i], bf_[j], acc[i][j]);                       \
} while (0)

#define GEMM_LOOP() do {                                                         \
    GSTAGE(0, 0); __syncthreads();                                               \
    for (int k0 = 0; k0 < CDIM; k0 += 64) {                                      \
        GSTAGE(k0 + 32, 1);                                                      \
        GCOMP(0);                                                                \
        __syncthreads();                                                         \
        GSTAGE((k0 + 64 < CDIM) ? k0 + 64 : 0, 0);                               \
        GCOMP(1);                                                                \
        __syncthreads();                                                         \
    }                                                                            \
} while (0)

__global__ __launch_bounds__(256) void gemm_qkv(
    const short* __restrict__ A /*wqt[2304][768]*/,
    const short* __restrict__ B /*xb [4096][768]*/,
    short* __restrict__ qb, short* __restrict__ kb, short* __restrict__ vt)
{
    __shared__ __align__(16) short As[8192];
    __shared__ __align__(16) short Bs[16384];
    const int t = threadIdx.x;
    const int lane = t & 63, wid = t >> 6;
    const int quad = lane >> 4, l16 = lane & 15;
    const int wA = wid >> 1, wB = wid & 1;
    const int n0 = blockIdx.x * 64;
    const int m0 = blockIdx.y * 128;

    const short* ag  = A + (size_t)(n0 + wid*16 + (lane >> 2)) * CDIM + (lane & 3)*8;
    const short* bg0 = B + (size_t)(m0 + wid*32 + (lane >> 2)) * CDIM + (lane & 3)*8;
    const short* bg1 = bg0 + (size_t)16 * CDIM;

    f32x4 acc[2][4] = {};
    GEMM_LOOP();

    const int s = n0 / CDIM;
    const int h = (n0 - s * CDIM) >> 6;
    const int b = m0 >> 11;
    const size_t bh = (size_t)(b * NH + h);
    const float qsc = (s == 0) ? 0.125f : 1.0f;
    #pragma unroll
    for (int i = 0; i < 2; ++i) {
        const int d0 = wA*32 + i*16 + quad*4;
        #pragma unroll
        for (int j = 0; j < 4; ++j) {
            int tok = (m0 & (NSEQ - 1)) + wB*64 + j*16 + l16;
            if (s < 2) {
                short* dst = (s == 0 ? qb : kb) + (bh * NSEQ + tok) * HD + d0;
                short4v o = { f2b(acc[i][j][0]*qsc), f2b(acc[i][j][1]*qsc),
                              f2b(acc[i][j][2]*qsc), f2b(acc[i][j][3]*qsc) };
                *(short4v*)dst = o;
            } else {
                short* dst = vt + (bh * HD + d0) * NSEQ + tok;
                #pragma unroll
                for (int r = 0; r < 4; ++r)
                    dst[(size_t)r * NSEQ] = f2b(acc[i][j][r]);
            }
        }
    }
}

// ---------------------------------------------------------------------------
// Flash attention v11: v8 pipeline with 512-thread blocks (8 waves).
// Waves 0-3 compute queries [q0,q0+64), waves 4-7 queries [q0+64,q0+128);
// all share the same dbuf K/V staging (per-wave staging halves). 1 barrier
// per 128-key tile. Epilogue: 128-query O buffer.
// ---------------------------------------------------------------------------
#define STAGE(KT, BUF) do {                                                      \
    short* kb_ = (BUF);                                                          \
    short* vb_ = (BUF) + 8192;                                                   \
    _Pragma("unroll")                                                            \
    for (int j = 0; j < 2; ++j) {                                                \
        gll16(kp + (size_t)((KT) + rK[j]) * HD + cK[j]*8,                        \
              kb_ + wid*1024 + j*512);                                           \
        gll16(vp + (size_t)dV[j] * NSEQ + (KT) + cV[j]*8,                        \
              vb_ + wid*1024 + j*512);                                           \
    }                                                                            \
} while (0)

#define BODY(KT, BUF) do {                                                       \
    const short* KsB_ = (BUF);                                                   \
    const short* VsB_ = (BUF) + 8192;                                            \
    int4 mi0_ = *(const int4*)(mp + (KT) + kbase);                               \
    int4 mi1_ = *(const int4*)(mp + (KT) + 64 + kbase);                          \
    bf16x8 kf00_ = *(const bf16x8*)&KsB_[krow + kc0];                            \
    bf16x8 kf01_ = *(const bf16x8*)&KsB_[krow + kc1];                            \
    bf16x8 kf10_ = *(const bf16x8*)&KsB_[4096 + krow + kc0];                     \
    bf16x8 kf11_ = *(const bf16x8*)&KsB_[4096 + krow + kc1];                     \
    f32x4 s0_[4] = {}, s1_[4] = {};                                              \
    _Pragma("unroll")                                                            \
    for (int jt = 0; jt < 4; ++jt) {                                             \
        s0_[jt] = MFMA16(kf00_, qf[jt][0], s0_[jt]);                             \
        s0_[jt] = MFMA16(kf01_, qf[jt][1], s0_[jt]);                             \
        s1_[jt] = MFMA16(kf10_, qf[jt][0], s1_[jt]);                             \
        s1_[jt] = MFMA16(kf11_, qf[jt][1], s1_[jt]);                             \
    }                                                                            \
    float4 m0_ = {(float)mi0_.x, (float)mi0_.y, (float)mi0_.z, (float)mi0_.w};   \
    float4 m1_ = {(float)mi1_.x, (float)mi1_.y, (float)mi1_.z, (float)mi1_.w};   \
    bf16x8 pb_[4];                                                               \
    _Pragma("unroll")                                                            \
    for (int jt = 0; jt < 4; ++jt) {                                             \
        float e0 = __expf(s0_[jt][0]) * m0_.x;                                   \
        float e1 = __expf(s0_[jt][1]) * m0_.y;                                   \
        float e2 = __expf(s0_[jt][2]) * m0_.z;                                   \
        float e3 = __expf(s0_[jt][3]) * m0_.w;                                   \
        float f0 = __expf(s1_[jt][0]) * m1_.x;                                   \
        float f1 = __expf(s1_[jt][1]) * m1_.y;                                   \
        float f2 = __expf(s1_[jt][2]) * m1_.z;                                   \
        float f3 = __expf(s1_[jt][3]) * m1_.w;                                   \
        l[jt] += ((e0 + e1) + (e2 + e3)) + ((f0 + f1) + (f2 + f3));              \
        uint4v pk_ = { pack2(e0, e1), pack2(e2, e3),                             \
                       pack2(f0, f1), pack2(f2, f3) };                           \
        pb_[jt] = __builtin_bit_cast(bf16x8, pk_);                               \
    }                                                                            \
    _Pragma("unroll")                                                            \
    for (int it = 0; it < 4; ++it) {                                             \
        const int vrow_ = (it*16 + l16) * 128;                                   \
        bf16x4 lo_ = *(const bf16x4*)&VsB_[vrow_ + vposl + vsub];                \
        bf16x4 hi_ = *(const bf16x4*)&VsB_[vrow_ + vposh + vsub];                \
        bf16x8 vf_ = __builtin_shufflevector(lo_, hi_, 0,1,2,3,4,5,6,7);         \
        _Pragma("unroll")                                                        \
        for (int jt = 0; jt < 4; ++jt)                                           \
            o_acc[it][jt] = MFMA16(vf_, pb_[jt], o_acc[it][jt]);                 \
    }                                                                            \
} while (0)

__global__ __launch_bounds__(512, 4) void attn_kernel(
    const short* __restrict__ qb, const short* __restrict__ kb,
    const short* __restrict__ vt, const int* __restrict__ mask,
    short* __restrict__ ao)
{
    __shared__ __align__(16) short KV[2][16384];    // [buf][K 16KB | V 16KB]
    float (*Ob)[136] = (float(*)[136])KV;           // epilogue alias: 64x136 f32
    float (*lsum)[64] = (float(*)[64])((char*)KV + 34816);

    const int t = threadIdx.x;
    const int lane = t & 63, wid = t >> 6;          // wid 0..7
    const int w4 = wid & 3, whalf = wid >> 2;
    const int quad = lane >> 4, l16 = lane & 15;
    // XCD swizzle: XCD = id%8 owns bh in {xcd, xcd+8, xcd+16}
    const int id = blockIdx.x;
    const int idx = id >> 3;                        // 0..47
    const int bh = (id & 7) + ((idx % 3) << 3);
    const int q0 = (idx / 3) << 7;                  // 128-query blocks
    const int b = bh / NH, h = bh - b * NH;
    const size_t hoff = (size_t)bh * NSEQ * HD;
    const short* qp = qb + hoff;     // [N][64]  (q pre-scaled by 0.125)
    const short* kp = kb + hoff;     // [N][64]
    const short* vp = vt + hoff;     // [64][N]
    const int* mp = mask + b * NSEQ;
    const int kbase = w4 * 16 + quad * 4;

    // staging decode (8 waves, 2 x 16B chunks each per buffer side)
    int rK[2], cK[2], dV[2], cV[2];
    #pragma unroll
    for (int j = 0; j < 2; ++j) {
        int o = wid * 2048 + j * 1024 + lane * 16;
        rK[j] = o >> 7;                          // K row (key), 128B rows
        cK[j] = ((o >> 4) & 7) ^ (rK[j] & 7);
        dV[j] = o >> 8;                          // V row (d), 256B rows
        cV[j] = ((o >> 4) & 15) ^ (dV[j] & 15);
    }
    const int r7 = l16 & 7;
    const int krow = (w4 * 16 + l16) * 64;
    const int kc0 = ((quad     ^ r7) << 3);
    const int kc1 = (((quad+4) ^ r7) << 3);
    const int vposl = ((w4*2 + (quad >> 1)) ^ l16) << 3;
    const int vposh = (((8 + w4*2 + (quad >> 1)) ^ l16) << 3);
    const int vsub = (quad & 1) * 4;

    // Q fragments: this wave's 64-query half
    bf16x8 qf[4][2];
    #pragma unroll
    for (int jt = 0; jt < 4; ++jt) {
        const short* qr = qp + (size_t)(q0 + whalf*64 + jt*16 + l16) * HD + quad*8;
        qf[jt][0] = *(const bf16x8*)qr;
        qf[jt][1] = *(const bf16x8*)(qr + 32);
    }

    f32x4 o_acc[4][4] = {};
    float l[4] = {0.f, 0.f, 0.f, 0.f};

    STAGE(0, KV[0]);
    __syncthreads();

    for (int kt = 0; kt < NSEQ; kt += 256) {
        STAGE(kt + 128, KV[1]);
        BODY(kt, KV[0]);
        __syncthreads();
        const int nx = (kt + 256) & (NSEQ - 1);
        STAGE(nx, KV[0]);
        BODY(kt + 128, KV[1]);
        __syncthreads();
    }

    // ---- epilogue: cross-wave O/l reduction over each query half ----
    #pragma unroll
    for (int jt = 0; jt < 4; ++jt) {
        l[jt] += __shfl_xor(l[jt], 16);
        l[jt] += __shfl_xor(l[jt], 32);
        if (quad == 0) lsum[wid][jt*16 + l16] = l[jt];
    }
    for (int w = 0; w < 8; ++w) {
        __syncthreads();
        if (wid == w) {
            const int qc = whalf * 64;
            #pragma unroll
            for (int it = 0; it < 4; ++it)
                #pragma unroll
                for (int jt = 0; jt < 4; ++jt)
                    #pragma unroll
                    for (int r = 0; r < 4; ++r) {
                        float* p = &Ob[it*16 + quad*4 + r][qc + jt*16 + l16];
                        if (w == 0 || w == 4) *p = o_acc[it][jt][r];
                        else                  *p += o_acc[it][jt][r];
                    }
        }
    }
    __syncthreads();

    {
        const int ql = t >> 2, dc = (t & 3) * 16;   // ql 0..127
        const int qq = ql & 63, wb = (ql >> 6) * 4;
        float inv = 1.0f / (((lsum[wb+0][qq] + lsum[wb+1][qq]) +
                             (lsum[wb+2][qq] + lsum[wb+3][qq])));
        bf16x8 o8a, o8b;
        #pragma unroll
        for (int d = 0; d < 8; ++d) o8a[d] = f2b(Ob[dc + d][ql] * inv);
        #pragma unroll
        for (int d = 0; d < 8; ++d) o8b[d] = f2b(Ob[dc + 8 + d][ql] * inv);
        int tok = b * NSEQ + q0 + ql;
        short* dst = ao + (size_t)tok * CDIM + h * HD + dc;
        *(bf16x8*)dst = o8a;
        *(bf16x8*)(dst + 8) = o8b;
    }
}

// ---------------------------------------------------------------------------
// GEMM2: 64x128 tile, grid 384 (round 11).
// ---------------------------------------------------------------------------
__global__ __launch_bounds__(256) void gemm_proj(
    const short* __restrict__ A /*wpt[768][768]*/,
    const short* __restrict__ B /*ao [4096][768]*/,
    const float* __restrict__ bias, float* __restrict__ out)
{
    __shared__ __align__(16) short As[8192];
    __shared__ __align__(16) short Bs[16384];
    const int t = threadIdx.x;
    const int lane = t & 63, wid = t >> 6;
    const int quad = lane >> 4, l16 = lane & 15;
    const int wA = wid >> 1, wB = wid & 1;
    const int n0 = blockIdx.x * 64;
    const int m0 = blockIdx.y * 128;

    const short* ag  = A + (size_t)(n0 + wid*16 + (lane >> 2)) * CDIM + (lane & 3)*8;
    const short* bg0 = B + (size_t)(m0 + wid*32 + (lane >> 2)) * CDIM + (lane & 3)*8;
    const short* bg1 = bg0 + (size_t)16 * CDIM;

    f32x4 acc[2][4] = {};
    GEMM_LOOP();

    #pragma unroll
    for (int i = 0; i < 2; ++i) {
        int col0 = n0 + wA*32 + i*16 + quad*4;
        float4 bias4 = *(const float4*)&bias[col0];
        #pragma unroll
        for (int j = 0; j < 4; ++j) {
            int tok = m0 + wB*64 + j*16 + l16;
            float4 o = { acc[i][j][0] + bias4.x, acc[i][j][1] + bias4.y,
                         acc[i][j][2] + bias4.z, acc[i][j][3] + bias4.w };
            *(float4*)(out + (size_t)tok * CDIM + col0) = o;
        }
    }
}

extern "C" void kernel_launch(void* const* d_in, const int* in_sizes, int n_in,
                              void* d_out, int out_size, void* d_ws, size_t ws_size,
                              hipStream_t stream)
{
    const float* x      = (const float*)d_in[0];
    const int*   mask   = (const int*)d_in[1];
    const float* w_qkv  = (const float*)d_in[2];
    const float* w_proj = (const float*)d_in[3];
    const float* b_proj = (const float*)d_in[4];
    float* out = (float*)d_out;

    const size_t SZ = (size_t)NTOK * CDIM;       // 3,145,728
    short* xb  = (short*)d_ws;                   // [4096][768]
    short* wqt = xb  + SZ;                       // [2304][768]
    short* wpt = wqt + (size_t)QKV_COLS * CDIM;  // [768][768]
    short* qb  = wpt + (size_t)CDIM * CDIM;      // [BH][N][64] (q pre-scaled)
    short* kb  = qb  + SZ;                       // [BH][N][64]
    short* vt  = kb  + SZ;                       // [BH][64][N]
    short* ao  = vt  + SZ;                       // [4096][768]

    prep_kernel<<<dim3(5376), dim3(256), 0, stream>>>(x, w_qkv, w_proj, xb, wqt, wpt);
    gemm_qkv<<<dim3(QKV_COLS/64, NTOK/128), dim3(256), 0, stream>>>(wqt, xb, qb, kb, vt);
    attn_kernel<<<dim3(NBLK), dim3(512), 0, stream>>>(qb, kb, vt, mask, ao);
    gemm_proj<<<dim3(CDIM/64, NTOK/128), dim3(256), 0, stream>>>(wpt, ao, b_proj, out);
}

// Round 13
// 176.043 us; speedup vs baseline: 2.2932x; 2.2932x over previous
//
#include <hip/hip_runtime.h>
#include <cstdint>

#define NB 2
#define NSEQ 2048
#define CDIM 768
#define NH 12
#define HD 64
#define NTOK (NB*NSEQ)        // 4096
#define QKV_COLS (3*CDIM)     // 2304
#define NBLK ((NSEQ/64)*NH*NB) // 768 attn blocks

typedef short bf16x8 __attribute__((ext_vector_type(8)));
typedef short bf16x4 __attribute__((ext_vector_type(4)));
typedef float f32x4  __attribute__((ext_vector_type(4)));
typedef short short4v __attribute__((ext_vector_type(4)));
typedef unsigned int uint4v __attribute__((ext_vector_type(4)));

#define MFMA16(a,b,c) __builtin_amdgcn_mfma_f32_16x16x32_bf16(a,b,c,0,0,0)

__device__ __forceinline__ short f2b(float f) {
    uint32_t u = __builtin_bit_cast(uint32_t, f);
    u += 0x7fffu + ((u >> 16) & 1u);
    return (short)(u >> 16);
}
__device__ __forceinline__ unsigned pack2(float a, float b) {
    unsigned ua = __builtin_bit_cast(unsigned, a) + 0x7fffu;
    unsigned ub = __builtin_bit_cast(unsigned, b) + 0x7fffu;
    return __builtin_amdgcn_perm(ub, ua, 0x07060302u);
}
__device__ __forceinline__ void gll16(const short* g, short* l) {
    __builtin_amdgcn_global_load_lds(
        (const __attribute__((address_space(1))) unsigned int*)g,
        (__attribute__((address_space(3))) unsigned int*)l, 16, 0, 0);
}

// ---------------------------------------------------------------------------
// Merged prep: x fp32->bf16 (blocks 0..3071), w_qkv transpose (..4799),
// w_proj transpose (..5375).
// ---------------------------------------------------------------------------
__global__ __launch_bounds__(256) void prep_kernel(
    const float* __restrict__ x, const float* __restrict__ w_qkv,
    const float* __restrict__ w_proj,
    short* __restrict__ xb, short* __restrict__ wqt, short* __restrict__ wpt)
{
    __shared__ float tile[32][33];
    const int bid = blockIdx.x, t = threadIdx.x;
    if (bid < 3072) {
        int i = bid * 256 + t;
        float4 v = ((const float4*)x)[i];
        short4v o = { f2b(v.x), f2b(v.y), f2b(v.z), f2b(v.w) };
        ((short4v*)xb)[i] = o;
        return;
    }
    const float* w; short* wt; int K, NC, n0, k0;
    if (bid < 3072 + 1728) {
        int r = bid - 3072;
        w = w_qkv; wt = wqt; K = CDIM; NC = QKV_COLS;
        n0 = (r % 72) * 32; k0 = (r / 72) * 32;
    } else {
        int r = bid - 4800;
        w = w_proj; wt = wpt; K = CDIM; NC = CDIM;
        n0 = (r % 24) * 32; k0 = (r / 24) * 32;
    }
    #pragma unroll
    for (int i = 0; i < 4; ++i) {
        int idx = t + i * 256; int r = idx >> 5, c = idx & 31;
        tile[r][c] = w[(size_t)(k0 + r) * NC + n0 + c];
    }
    __syncthreads();
    #pragma unroll
    for (int i = 0; i < 4; ++i) {
        int idx = t + i * 256; int r = idx >> 5, c = idx & 31;
        wt[(size_t)(n0 + r) * K + k0 + c] = f2b(tile[c][r]);
    }
}

// ---------------------------------------------------------------------------
// GEMM1 (m97-style). Epilogue: q is PRE-SCALED by 0.125 (softmax scale).
// ---------------------------------------------------------------------------
__global__ __launch_bounds__(256) void gemm_qkv(
    const short* __restrict__ A /*wqt[2304][768]*/,
    const short* __restrict__ B /*xb [4096][768]*/,
    short* __restrict__ qb, short* __restrict__ kb, short* __restrict__ vt)
{
    __shared__ short As[128 * 32];
    __shared__ short Bs[128 * 32];
    const int t = threadIdx.x;
    const int lane = t & 63, wid = t >> 6;
    const int quad = lane >> 4, l16 = lane & 15;
    const int wA = wid >> 1, wB = wid & 1;
    const int n0 = blockIdx.x * 128;
    const int m0 = blockIdx.y * 128;

    const int srow = wid * 16 + (lane >> 2), schunk = (lane & 3) * 8;
    const short* ag0 = A + (size_t)(n0 + srow) * CDIM + schunk;
    const short* ag1 = ag0 + (size_t)64 * CDIM;
    const short* bg0 = B + (size_t)(m0 + srow) * CDIM + schunk;
    const short* bg1 = bg0 + (size_t)64 * CDIM;
    short* asl0 = &As[(wid * 16) * 32];
    short* asl1 = &As[(wid * 16 + 64) * 32];
    short* bsl0 = &Bs[(wid * 16) * 32];
    short* bsl1 = &Bs[(wid * 16 + 64) * 32];

    f32x4 acc[4][4] = {};
    for (int k0 = 0; k0 < CDIM; k0 += 32) {
        __syncthreads();
        gll16(ag0 + k0, asl0);
        gll16(ag1 + k0, asl1);
        gll16(bg0 + k0, bsl0);
        gll16(bg1 + k0, bsl1);
        __syncthreads();
        bf16x8 af[4], bf[4];
        #pragma unroll
        for (int i = 0; i < 4; ++i)
            af[i] = *(const bf16x8*)&As[(wA*64 + i*16 + l16) * 32 + quad*8];
        #pragma unroll
        for (int j = 0; j < 4; ++j)
            bf[j] = *(const bf16x8*)&Bs[(wB*64 + j*16 + l16) * 32 + quad*8];
        #pragma unroll
        for (int i = 0; i < 4; ++i)
            #pragma unroll
            for (int j = 0; j < 4; ++j)
                acc[i][j] = MFMA16(af[i], bf[j], acc[i][j]);
    }

    const int colbase = n0 + wA * 64;
    const int s = colbase / CDIM;
    const int h = (colbase - s * CDIM) >> 6;
    const int b = m0 >> 11;
    const size_t bh = (size_t)(b * NH + h);
    const float qsc = (s == 0) ? 0.125f : 1.0f;   // fold softmax scale into q
    #pragma unroll
    for (int i = 0; i < 4; ++i) {
        const int d0 = i*16 + quad*4;
        #pragma unroll
        for (int j = 0; j < 4; ++j) {
            int tok = (m0 + wB*64 + j*16 + l16) & (NSEQ - 1);
            if (s < 2) {
                short* dst = (s == 0 ? qb : kb) + (bh * NSEQ + tok) * HD + d0;
                short4v o = { f2b(acc[i][j][0] * qsc), f2b(acc[i][j][1] * qsc),
                              f2b(acc[i][j][2] * qsc), f2b(acc[i][j][3] * qsc) };
                *(short4v*)dst = o;
            } else {
                short* dst = vt + (bh * HD + d0) * NSEQ + tok;
                #pragma unroll
                for (int r = 0; r < 4; ++r)
                    dst[(size_t)r * NSEQ] = f2b(acc[i][j][r]);
            }
        }
    }
}

// ---------------------------------------------------------------------------
// Flash attention v8 (measured best: 59.0 us): cooperative swizzled K+V
// staging, DOUBLE-buffered in LDS (2 x 32 KB), stage i+1 -> body i -> ONE
// barrier per 128-key tile. P stays in registers (S^T = K*Q^T layout trick).
// NOTE: needs ~128 VGPR/lane. Any config implying a <128 VGPR budget
// (register ping-pong, 512-thread blocks with >=2 blocks/CU) SPILLS
// catastrophically [measured rounds 7 and 12].
// ---------------------------------------------------------------------------
#define STAGE(KT, BUF) do {                                                      \
    short* kb_ = (BUF);                                                          \
    short* vb_ = (BUF) + 8192;                                                   \
    _Pragma("unroll")                                                            \
    for (int j = 0; j < 4; ++j) {                                                \
        gll16(kp + (size_t)((KT) + rK[j]) * HD + cK[j]*8,                        \
              kb_ + wid*2048 + j*512);                                           \
        gll16(vp + (size_t)dV[j] * NSEQ + (KT) + cV[j]*8,                        \
              vb_ + wid*2048 + j*512);                                           \
    }                                                                            \
} while (0)

#define BODY(KT, BUF) do {                                                       \
    const short* KsB_ = (BUF);                                                   \
    const short* VsB_ = (BUF) + 8192;                                            \
    int4 mi0_ = *(const int4*)(mp + (KT) + kbase);                               \
    int4 mi1_ = *(const int4*)(mp + (KT) + 64 + kbase);                          \
    bf16x8 kf00_ = *(const bf16x8*)&KsB_[krow + kc0];                            \
    bf16x8 kf01_ = *(const bf16x8*)&KsB_[krow + kc1];                            \
    bf16x8 kf10_ = *(const bf16x8*)&KsB_[4096 + krow + kc0];                     \
    bf16x8 kf11_ = *(const bf16x8*)&KsB_[4096 + krow + kc1];                     \
    f32x4 s0_[4] = {}, s1_[4] = {};                                              \
    _Pragma("unroll")                                                            \
    for (int jt = 0; jt < 4; ++jt) {                                             \
        s0_[jt] = MFMA16(kf00_, qf[jt][0], s0_[jt]);                             \
        s0_[jt] = MFMA16(kf01_, qf[jt][1], s0_[jt]);                             \
        s1_[jt] = MFMA16(kf10_, qf[jt][0], s1_[jt]);                             \
        s1_[jt] = MFMA16(kf11_, qf[jt][1], s1_[jt]);                             \
    }                                                                            \
    float4 m0_ = {(float)mi0_.x, (float)mi0_.y, (float)mi0_.z, (float)mi0_.w};   \
    float4 m1_ = {(float)mi1_.x, (float)mi1_.y, (float)mi1_.z, (float)mi1_.w};   \
    bf16x8 pb_[4];                                                               \
    _Pragma("unroll")                                                            \
    for (int jt = 0; jt < 4; ++jt) {                                             \
        float e0 = __expf(s0_[jt][0]) * m0_.x;                                   \
        float e1 = __expf(s0_[jt][1]) * m0_.y;                                   \
        float e2 = __expf(s0_[jt][2]) * m0_.z;                                   \
        float e3 = __expf(s0_[jt][3]) * m0_.w;                                   \
        float f0 = __expf(s1_[jt][0]) * m1_.x;                                   \
        float f1 = __expf(s1_[jt][1]) * m1_.y;                                   \
        float f2 = __expf(s1_[jt][2]) * m1_.z;                                   \
        float f3 = __expf(s1_[jt][3]) * m1_.w;                                   \
        l[jt] += ((e0 + e1) + (e2 + e3)) + ((f0 + f1) + (f2 + f3));              \
        uint4v pk_ = { pack2(e0, e1), pack2(e2, e3),                             \
                       pack2(f0, f1), pack2(f2, f3) };                           \
        pb_[jt] = __builtin_bit_cast(bf16x8, pk_);                               \
    }                                                                            \
    _Pragma("unroll")                                                            \
    for (int it = 0; it < 4; ++it) {                                             \
        const int vrow_ = (it*16 + l16) * 128;                                   \
        bf16x4 lo_ = *(const bf16x4*)&VsB_[vrow_ + vposl + vsub];                \
        bf16x4 hi_ = *(const bf16x4*)&VsB_[vrow_ + vposh + vsub];                \
        bf16x8 vf_ = __builtin_shufflevector(lo_, hi_, 0,1,2,3,4,5,6,7);         \
        _Pragma("unroll")                                                        \
        for (int jt = 0; jt < 4; ++jt)                                           \
            o_acc[it][jt] = MFMA16(vf_, pb_[jt], o_acc[it][jt]);                 \
    }                                                                            \
} while (0)

__global__ __launch_bounds__(256, 2) void attn_kernel(
    const short* __restrict__ qb, const short* __restrict__ kb,
    const short* __restrict__ vt, const int* __restrict__ mask,
    short* __restrict__ ao)
{
    __shared__ __align__(16) short KV[2][16384];   // [buf][K 16KB | V 16KB]
    float (*Ob)[68] = (float(*)[68])KV;            // epilogue alias
    float (*lsum)[64] = (float(*)[64])((char*)KV + 17408);

    const int t = threadIdx.x;
    const int lane = t & 63, wid = t >> 6;
    const int quad = lane >> 4, l16 = lane & 15;
    // XCD swizzle: XCD = id%8 owns bh in {xcd, xcd+8, xcd+16}
    const int id = blockIdx.x;
    const int idx = id >> 3;
    const int bh = (id & 7) + ((idx % 3) << 3);
    const int q0 = (idx / 3) << 6;
    const int b = bh / NH, h = bh - b * NH;
    const size_t hoff = (size_t)bh * NSEQ * HD;
    const short* qp = qb + hoff;     // [N][64]  (q pre-scaled by 0.125)
    const short* kp = kb + hoff;     // [N][64]
    const short* vp = vt + hoff;     // [64][N]
    const int* mp = mask + b * NSEQ;
    const int kbase = wid * 16 + quad * 4;

    int rK[4], cK[4], dV[4], cV[4];
    #pragma unroll
    for (int j = 0; j < 4; ++j) {
        int o = wid * 4096 + j * 1024 + lane * 16;
        rK[j] = o >> 7;
        cK[j] = ((o >> 4) & 7) ^ (rK[j] & 7);
        dV[j] = o >> 8;
        cV[j] = ((o >> 4) & 15) ^ (dV[j] & 15);
    }
    const int r7 = l16 & 7;
    const int krow = (wid * 16 + l16) * 64;
    const int kc0 = ((quad     ^ r7) << 3);
    const int kc1 = (((quad+4) ^ r7) << 3);
    const int vposl = ((wid*2 + (quad >> 1)) ^ l16) << 3;
    const int vposh = (((8 + wid*2 + (quad >> 1)) ^ l16) << 3);
    const int vsub = (quad & 1) * 4;

    bf16x8 qf[4][2];
    #pragma unroll
    for (int jt = 0; jt < 4; ++jt) {
        const short* qr = qp + (size_t)(q0 + jt*16 + l16) * HD + quad*8;
        qf[jt][0] = *(const bf16x8*)qr;
        qf[jt][1] = *(const bf16x8*)(qr + 32);
    }

    f32x4 o_acc[4][4] = {};
    float l[4] = {0.f, 0.f, 0.f, 0.f};

    STAGE(0, KV[0]);
    __syncthreads();

    for (int kt = 0; kt < NSEQ; kt += 256) {
        STAGE(kt + 128, KV[1]);
        BODY(kt, KV[0]);
        __syncthreads();
        const int nx = (kt + 256) & (NSEQ - 1);
        STAGE(nx, KV[0]);
        BODY(kt + 128, KV[1]);
        __syncthreads();
    }

    #pragma unroll
    for (int jt = 0; jt < 4; ++jt) {
        l[jt] += __shfl_xor(l[jt], 16);
        l[jt] += __shfl_xor(l[jt], 32);
        if (quad == 0) lsum[wid][jt*16 + l16] = l[jt];
    }
    for (int w = 0; w < 4; ++w) {
        __syncthreads();
        if (wid == w) {
            #pragma unroll
            for (int it = 0; it < 4; ++it)
                #pragma unroll
                for (int jt = 0; jt < 4; ++jt)
                    #pragma unroll
                    for (int r = 0; r < 4; ++r) {
                        if (w == 0)
                            Ob[it*16 + quad*4 + r][jt*16 + l16] = o_acc[it][jt][r];
                        else
                            Ob[it*16 + quad*4 + r][jt*16 + l16] += o_acc[it][jt][r];
                    }
        }
    }
    __syncthreads();

    {
        const int ql = t >> 2, dc = (t & 3) * 16;
        float inv = 1.0f / (((lsum[0][ql] + lsum[1][ql]) +
                             (lsum[2][ql] + lsum[3][ql])));
        bf16x8 o8a, o8b;
        #pragma unroll
        for (int d = 0; d < 8; ++d) o8a[d] = f2b(Ob[dc + d][ql] * inv);
        #pragma unroll
        for (int d = 0; d < 8; ++d) o8b[d] = f2b(Ob[dc + 8 + d][ql] * inv);
        int tok = b * NSEQ + q0 + ql;
        short* dst = ao + (size_t)tok * CDIM + h * HD + dc;
        *(bf16x8*)dst = o8a;
        *(bf16x8*)(dst + 8) = o8b;
    }
}

// ---------------------------------------------------------------------------
// GEMM2 (m97-style, round-8 verbatim)
// ---------------------------------------------------------------------------
__global__ __launch_bounds__(256) void gemm_proj(
    const short* __restrict__ A /*wpt[768][768]*/,
    const short* __restrict__ B /*ao [4096][768]*/,
    const float* __restrict__ bias, float* __restrict__ out)
{
    __shared__ short As[128 * 32];
    __shared__ short Bs[128 * 32];
    const int t = threadIdx.x;
    const int lane = t & 63, wid = t >> 6;
    const int quad = lane >> 4, l16 = lane & 15;
    const int wA = wid >> 1, wB = wid & 1;
    const int n0 = blockIdx.x * 128;
    const int m0 = blockIdx.y * 128;

    const int srow = wid * 16 + (lane >> 2), schunk = (lane & 3) * 8;
    const short* ag0 = A + (size_t)(n0 + srow) * CDIM + schunk;
    const short* ag1 = ag0 + (size_t)64 * CDIM;
    const short* bg0 = B + (size_t)(m0 + srow) * CDIM + schunk;
    const short* bg1 = bg0 + (size_t)64 * CDIM;
    short* asl0 = &As[(wid * 16) * 32];
    short* asl1 = &As[(wid * 16 + 64) * 32];
    short* bsl0 = &Bs[(wid * 16) * 32];
    short* bsl1 = &Bs[(wid * 16 + 64) * 32];

    f32x4 acc[4][4] = {};
    for (int k0 = 0; k0 < CDIM; k0 += 32) {
        __syncthreads();
        gll16(ag0 + k0, asl0);
        gll16(ag1 + k0, asl1);
        gll16(bg0 + k0, bsl0);
        gll16(bg1 + k0, bsl1);
        __syncthreads();
        bf16x8 af[4], bf[4];
        #pragma unroll
        for (int i = 0; i < 4; ++i)
            af[i] = *(const bf16x8*)&As[(wA*64 + i*16 + l16) * 32 + quad*8];
        #pragma unroll
        for (int j = 0; j < 4; ++j)
            bf[j] = *(const bf16x8*)&Bs[(wB*64 + j*16 + l16) * 32 + quad*8];
        #pragma unroll
        for (int i = 0; i < 4; ++i)
            #pragma unroll
            for (int j = 0; j < 4; ++j)
                acc[i][j] = MFMA16(af[i], bf[j], acc[i][j]);
    }

    #pragma unroll
    for (int i = 0; i < 4; ++i) {
        int col0 = n0 + wA*64 + i*16 + quad*4;
        float4 bias4 = *(const float4*)&bias[col0];
        #pragma unroll
        for (int j = 0; j < 4; ++j) {
            int tok = m0 + wB*64 + j*16 + l16;
            float4 o = { acc[i][j][0] + bias4.x, acc[i][j][1] + bias4.y,
                         acc[i][j][2] + bias4.z, acc[i][j][3] + bias4.w };
            *(float4*)(out + (size_t)tok * CDIM + col0) = o;
        }
    }
}

extern "C" void kernel_launch(void* const* d_in, const int* in_sizes, int n_in,
                              void* d_out, int out_size, void* d_ws, size_t ws_size,
                              hipStream_t stream)
{
    const float* x      = (const float*)d_in[0];
    const int*   mask   = (const int*)d_in[1];
    const float* w_qkv  = (const float*)d_in[2];
    const float* w_proj = (const float*)d_in[3];
    const float* b_proj = (const float*)d_in[4];
    float* out = (float*)d_out;

    const size_t SZ = (size_t)NTOK * CDIM;       // 3,145,728
    short* xb  = (short*)d_ws;                   // [4096][768]
    short* wqt = xb  + SZ;                       // [2304][768]
    short* wpt = wqt + (size_t)QKV_COLS * CDIM;  // [768][768]
    short* qb  = wpt + (size_t)CDIM * CDIM;      // [BH][N][64]  (pre-scaled q)
    short* kb  = qb  + SZ;                       // [BH][N][64]
    short* vt  = kb  + SZ;                       // [BH][64][N]
    short* ao  = vt  + SZ;                       // [4096][768]

    dim3 blk(256);
    prep_kernel<<<dim3(5376), blk, 0, stream>>>(x, w_qkv, w_proj, xb, wqt, wpt);
    gemm_qkv<<<dim3(QKV_COLS/128, NTOK/128), blk, 0, stream>>>(wqt, xb, qb, kb, vt);
    attn_kernel<<<dim3(NBLK), blk, 0, stream>>>(qb, kb, vt, mask, ao);
    gemm_proj<<<dim3(CDIM/128, NTOK/128), blk, 0, stream>>>(wpt, ao, b_proj, out);
}